// Round 4
// baseline (1537.222 us; speedup 1.0000x reference)
//
#include <hip/hip_runtime.h>

// ---------------- problem constants ----------------
#define T_TOKENS 8192
#define H_DIM    2048
#define I_DIM    4096
#define NE       8
#define NPAIR    16384                  // T_TOKENS * TOP_K
#define PADBM    256                    // expert segment padding (= BM of GEMM tiles)
#define PADP     (NPAIR + NE * PADBM)   // 18432 worst-case padded rows
#define RT_MAX   (PADP / PADBM)         // 72 max row tiles

// 256x256x64 8-phase GEMM geometry
#define BM2 256
#define BN2 256
#define BK2 64
#define NTHR 512

// ---------------- workspace layout (bytes) ----------------
// x_bf16 33.5MB | w_bf16 134.2MB (up -> down) | h_bf16 151MB | tok 74KB | ybuf 67MB | meta
#define WS_X    0ull
#define WS_W    (WS_X + (size_t)T_TOKENS * H_DIM * 2)
#define WS_H    (WS_W + (size_t)NE * I_DIM * H_DIM * 2)
#define WS_TOK  (WS_H + (size_t)PADP * I_DIM * 2)
#define WS_YB   (WS_TOK + (size_t)PADP * 4)
#define WS_META (WS_YB + (size_t)NPAIR * H_DIM * 2)

typedef __attribute__((ext_vector_type(8))) short bf16x8;   // 8 bf16 = 4 VGPRs
typedef __attribute__((ext_vector_type(4))) float f32x4;    // MFMA C/D

__device__ __forceinline__ unsigned short f2bf(float f) {
  union { float f; unsigned u; } a; a.f = f;
  unsigned r = a.u + 0x7fffu + ((a.u >> 16) & 1u);   // RNE
  return (unsigned short)(r >> 16);
}

__device__ __forceinline__ float b2f(unsigned short b) {
  union { unsigned u; float f; } a; a.u = ((unsigned)b) << 16;
  return a.f;
}

__device__ __forceinline__ void gload16(const void* g, void* l) {
  __builtin_amdgcn_global_load_lds(
      (const __attribute__((address_space(1))) unsigned int*)g,
      (__attribute__((address_space(3))) unsigned int*)l,
      16, 0, 0);
}

// ---------------- fp32 -> bf16 conversion ----------------
__global__ void cvt_f32_bf16(const float* __restrict__ in,
                             unsigned short* __restrict__ out, int n4) {
  int i = blockIdx.x * blockDim.x + threadIdx.x;
  int stride = gridDim.x * blockDim.x;
  for (; i < n4; i += stride) {
    float4 v = ((const float4*)in)[i];
    ushort4 o;
    o.x = f2bf(v.x); o.y = f2bf(v.y); o.z = f2bf(v.z); o.w = f2bf(v.w);
    ((ushort4*)out)[i] = o;
  }
}

// ---------------- routing ----------------
__global__ void route_count(const int* __restrict__ idx, int* __restrict__ meta) {
  int i = blockIdx.x * blockDim.x + threadIdx.x;
  if (i < NPAIR) atomicAdd(&meta[idx[i]], 1);
}

__global__ void route_scan(int* __restrict__ meta) {
  if (threadIdx.x == 0 && blockIdx.x == 0) {
    int off = 0;
    for (int e = 0; e < NE; ++e) {
      meta[16 + e] = off;
      int c = meta[e];
      off += ((c + PADBM - 1) / PADBM) * PADBM;
    }
    meta[16 + NE] = off;
  }
}

__global__ void route_scatter(const int* __restrict__ idx,
                              int* __restrict__ meta, int* __restrict__ tok) {
  int i = blockIdx.x * blockDim.x + threadIdx.x;
  if (i < NPAIR) {
    int e = idx[i];
    int pos = meta[16 + e] + atomicAdd(&meta[8 + e], 1);
    tok[pos] = i;                       // pair index; token = i>>1 (TOP_K=2)
  }
}

// ---------------- 8-phase 256^2 grouped-GEMM core ----------------
// LDS: A dbuf [2][8 kc][256 rows][16B] = 64KB at 0; B same at 65536. Total 128KB.
// c0 stages the ENTIRE next tile (8 loads); waits: vmcnt(8)@c1 (half1(t) ready
// for c2, issued 5 phases prior), vmcnt(4)@c3 (half0(t+1) ready for c0', issued
// 4 phases prior). Never drains to 0 in the main loop.

#define STAGE_FULL(KT, BS) do {                                                \
    _Pragma("unroll")                                                          \
    for (int hk_ = 0; hk_ < 2; ++hk_) {                                        \
      int ko_ = (KT) * 64 + hk_ * 32 + sub * 16;        /* shorts */           \
      char* lA_ = smem + (BS) * 32768 + (hk_ * 4 + sub * 2) * 4096 + r16;      \
      char* lB_ = smem + 65536 + (BS) * 32768 + (hk_ * 4 + sub * 2) * 4096 + r16;\
      gload16(apt + ko_,     lA_);                                             \
      gload16(apt + ko_ + 8, lA_ + 4096);                                      \
      gload16(bpt + ko_,     lB_);                                             \
      gload16(bpt + ko_ + 8, lB_ + 4096);                                      \
    }                                                                          \
  } while (0)

#define PHASE(KS, FH, DO_STAGE, DO_VM) do {                                    \
    bf16x8 af[4];                                                              \
    const char* aB_ = smem + bufc * 32768 + ((KS) * 4 + hi) * 4096;            \
    _Pragma("unroll")                                                          \
    for (int f = 0; f < 4; ++f)                                                \
      af[f] = *(const bf16x8*)(aB_ + arow_b + ((FH) * 4 + f) * 256);           \
    if ((FH) == 0) {                                                           \
      const char* bB_ = smem + 65536 + bufc * 32768 + ((KS) * 4 + hi) * 4096;  \
      _Pragma("unroll")                                                        \
      for (int f = 0; f < 4; ++f)                                              \
        bfr[f] = *(const bf16x8*)(bB_ + brow_b + f * 256);                     \
    }                                                                          \
    DO_STAGE;                                                                  \
    DO_VM;                                                                     \
    __builtin_amdgcn_s_barrier();                                              \
    asm volatile("s_waitcnt lgkmcnt(0)" ::: "memory");                         \
    __builtin_amdgcn_s_setprio(1);                                             \
    _Pragma("unroll")                                                          \
    for (int fm = 0; fm < 4; ++fm)                                             \
      _Pragma("unroll")                                                        \
      for (int fn = 0; fn < 4; ++fn)                                           \
        acc[(FH) * 4 + fm][fn] = __builtin_amdgcn_mfma_f32_16x16x32_bf16(      \
            af[fm], bfr[fn], acc[(FH) * 4 + fm][fn], 0, 0, 0);                 \
    __builtin_amdgcn_s_setprio(0);                                             \
    __builtin_amdgcn_s_barrier();                                              \
  } while (0)

#define GEMM_PROLOGUE()                                                        \
  STAGE_FULL(0, 0);                                                            \
  asm volatile("s_waitcnt vmcnt(4)" ::: "memory");                             \
  __builtin_amdgcn_s_barrier();

#define GEMM_MAIN(NKT)                                                         \
  int bufc = 0;                                                                \
  for (int kt = 0; kt < (NKT); ++kt) {                                         \
    int ktn = (kt + 1 < (NKT)) ? kt + 1 : (NKT) - 1;  /* clamp: uniform counts */\
    int bn_ = bufc ^ 1;                                                        \
    PHASE(0, 0, STAGE_FULL(ktn, bn_), (void)0);                                \
    PHASE(0, 1, (void)0,                                                       \
          asm volatile("s_waitcnt vmcnt(8)" ::: "memory"));                    \
    PHASE(1, 0, (void)0, (void)0);                                             \
    PHASE(1, 1, (void)0,                                                       \
          asm volatile("s_waitcnt vmcnt(4)" ::: "memory"));                    \
    bufc ^= 1;                                                                 \
  }

// ---------------- GEMM1: h = relu2(x_gather @ up[e]^T) ----------------
__global__ __launch_bounds__(NTHR, 2) void gemm_up8(
    const unsigned short* __restrict__ X, const unsigned short* __restrict__ W,
    unsigned short* __restrict__ Hb, const int* __restrict__ meta,
    const int* __restrict__ tok) {
  extern __shared__ char smem[];
  const int* pstart = meta + 16;
  const int NTn = I_DIM / BN2;               // 16
  int rt = blockIdx.x / NTn, nt = blockIdx.x % NTn;
  int row0 = rt * BM2;
  if (row0 >= pstart[NE]) return;
  int e = 0;
  #pragma unroll
  for (int q = 1; q < NE; ++q) if (row0 >= pstart[q]) e = q;

  int tid = threadIdx.x;
  int wv = tid >> 6, lane = tid & 63;
  int r = tid & 255, sub = tid >> 8;         // stage row / kc-subgroup
  int r16 = r * 16;

  int v = tok[row0 + r];
  int tokA = v < 0 ? 0 : (v >> 1);           // pad rows read row 0
  const unsigned short* apt = X + (size_t)tokA * H_DIM;
  const unsigned short* bpt = W + (size_t)e * I_DIM * H_DIM
                                + (size_t)(nt * BN2 + r) * H_DIM;

  int wm = wv >> 2, wn = wv & 3;
  int hi = lane >> 4;
  int arow_b = (wm * 128 + (lane & 15)) * 16;   // byte offset of frag row base
  int brow_b = (wn * 64 + (lane & 15)) * 16;

  f32x4 acc[8][4] = {};
  bf16x8 bfr[4];

  GEMM_PROLOGUE();
  GEMM_MAIN(H_DIM / BK2);                    // 32 K-tiles

  // epilogue: relu2 -> bf16
  int crow0 = row0 + wm * 128 + (lane >> 4) * 4;
  int ccol0 = nt * BN2 + wn * 64 + (lane & 15);
  #pragma unroll
  for (int fm = 0; fm < 8; ++fm) {
    #pragma unroll
    for (int j = 0; j < 4; ++j) {
      int p = crow0 + fm * 16 + j;
      unsigned short* dst = Hb + (size_t)p * I_DIM + ccol0;
      #pragma unroll
      for (int fn = 0; fn < 4; ++fn) {
        float x = acc[fm][fn][j];
        x = x > 0.f ? x * x : 0.f;
        dst[fn * 16] = f2bf(x);
      }
    }
  }
}

// ---------------- GEMM2: ybuf[pair] = h @ down[e]^T  (bf16, no atomics) ----------------
__global__ __launch_bounds__(NTHR, 2) void gemm_down8(
    const unsigned short* __restrict__ Hb, const unsigned short* __restrict__ W,
    unsigned short* __restrict__ Yb, const int* __restrict__ meta,
    const int* __restrict__ tok) {
  extern __shared__ char smem[];
  const int* pstart = meta + 16;
  const int NTn = H_DIM / BN2;               // 8
  int rt = blockIdx.x / NTn, nt = blockIdx.x % NTn;
  int row0 = rt * BM2;
  if (row0 >= pstart[NE]) return;
  int e = 0;
  #pragma unroll
  for (int q = 1; q < NE; ++q) if (row0 >= pstart[q]) e = q;

  int tid = threadIdx.x;
  int wv = tid >> 6, lane = tid & 63;
  int r = tid & 255, sub = tid >> 8;
  int r16 = r * 16;

  const unsigned short* apt = Hb + (size_t)(row0 + r) * I_DIM;
  const unsigned short* bpt = W + (size_t)e * H_DIM * I_DIM
                                + (size_t)(nt * BN2 + r) * I_DIM;

  int wm = wv >> 2, wn = wv & 3;
  int hi = lane >> 4;
  int arow_b = (wm * 128 + (lane & 15)) * 16;
  int brow_b = (wn * 64 + (lane & 15)) * 16;

  f32x4 acc[8][4] = {};
  bf16x8 bfr[4];

  GEMM_PROLOGUE();
  GEMM_MAIN(I_DIM / BK2);                    // 64 K-tiles

  int crow0 = row0 + wm * 128 + (lane >> 4) * 4;
  int ccol0 = nt * BN2 + wn * 64 + (lane & 15);
  #pragma unroll
  for (int fm = 0; fm < 8; ++fm) {
    #pragma unroll
    for (int j = 0; j < 4; ++j) {
      int p = crow0 + fm * 16 + j;
      int i = tok[p];
      if (i < 0) continue;                   // padding row
      unsigned short* dst = Yb + (size_t)i * H_DIM + ccol0;
      #pragma unroll
      for (int fn = 0; fn < 4; ++fn)
        dst[fn * 16] = f2bf(acc[fm][fn][j]);
    }
  }
}

// ---------------- combine: out[t] = w0*y[2t] + w1*y[2t+1] ----------------
__global__ __launch_bounds__(256) void combine(
    const unsigned short* __restrict__ Yb, const float* __restrict__ tkw,
    float* __restrict__ out) {
  int t = blockIdx.x;
  int h0 = threadIdx.x * 8;
  float w0 = tkw[2 * t], w1 = tkw[2 * t + 1];
  bf16x8 ya = *(const bf16x8*)(Yb + (size_t)(2 * t) * H_DIM + h0);
  bf16x8 yb = *(const bf16x8*)(Yb + (size_t)(2 * t + 1) * H_DIM + h0);
  float* dst = out + (size_t)t * H_DIM + h0;
  float4 o0, o1;
  o0.x = w0 * b2f((unsigned short)ya[0]) + w1 * b2f((unsigned short)yb[0]);
  o0.y = w0 * b2f((unsigned short)ya[1]) + w1 * b2f((unsigned short)yb[1]);
  o0.z = w0 * b2f((unsigned short)ya[2]) + w1 * b2f((unsigned short)yb[2]);
  o0.w = w0 * b2f((unsigned short)ya[3]) + w1 * b2f((unsigned short)yb[3]);
  o1.x = w0 * b2f((unsigned short)ya[4]) + w1 * b2f((unsigned short)yb[4]);
  o1.y = w0 * b2f((unsigned short)ya[5]) + w1 * b2f((unsigned short)yb[5]);
  o1.z = w0 * b2f((unsigned short)ya[6]) + w1 * b2f((unsigned short)yb[6]);
  o1.w = w0 * b2f((unsigned short)ya[7]) + w1 * b2f((unsigned short)yb[7]);
  ((float4*)dst)[0] = o0;
  ((float4*)dst)[1] = o1;
}

// ---------------- launch ----------------
extern "C" void kernel_launch(void* const* d_in, const int* in_sizes, int n_in,
                              void* d_out, int out_size, void* d_ws, size_t ws_size,
                              hipStream_t stream) {
  const float* x   = (const float*)d_in[0];
  const int*   tki = (const int*)d_in[1];
  const float* tkw = (const float*)d_in[2];
  const float* up  = (const float*)d_in[3];
  const float* dn  = (const float*)d_in[4];
  float* out = (float*)d_out;
  char* ws = (char*)d_ws;

  unsigned short* xb  = (unsigned short*)(ws + WS_X);
  unsigned short* wb  = (unsigned short*)(ws + WS_W);
  unsigned short* hb  = (unsigned short*)(ws + WS_H);
  int*            tok = (int*)(ws + WS_TOK);
  unsigned short* yb  = (unsigned short*)(ws + WS_YB);
  int*            meta= (int*)(ws + WS_META);

  // opt in to 128KB dynamic LDS (idempotent, host-side, capture-safe)
  hipFuncSetAttribute((const void*)gemm_up8,
                      hipFuncAttributeMaxDynamicSharedMemorySize, 131072);
  hipFuncSetAttribute((const void*)gemm_down8,
                      hipFuncAttributeMaxDynamicSharedMemorySize, 131072);

  hipMemsetAsync(meta, 0, 128, stream);
  hipMemsetAsync(tok, 0xFF, (size_t)PADP * 4, stream);    // -1 = padding

  cvt_f32_bf16<<<2048, 256, 0, stream>>>(x, xb, T_TOKENS * H_DIM / 4);
  cvt_f32_bf16<<<4096, 256, 0, stream>>>(up, wb, NE * I_DIM * H_DIM / 4);

  route_count  <<<NPAIR / 256, 256, 0, stream>>>(tki, meta);
  route_scan   <<<1, 64, 0, stream>>>(meta);
  route_scatter<<<NPAIR / 256, 256, 0, stream>>>(tki, meta, tok);

  gemm_up8<<<RT_MAX * (I_DIM / BN2), NTHR, 131072, stream>>>(xb, wb, hb, meta, tok);

  cvt_f32_bf16<<<4096, 256, 0, stream>>>(dn, wb, NE * H_DIM * I_DIM / 4);

  gemm_down8<<<RT_MAX * (H_DIM / BN2), NTHR, 131072, stream>>>(hb, wb, yb, meta, tok);

  combine<<<T_TOKENS, 256, 0, stream>>>(yb, tkw, out);
}

// Round 5
// 1172.652 us; speedup vs baseline: 1.3109x; 1.3109x over previous
//
#include <hip/hip_runtime.h>

// ---------------- problem constants ----------------
#define T_TOKENS 8192
#define H_DIM    2048
#define I_DIM    4096
#define NE       8
#define NPAIR    16384                  // T_TOKENS * TOP_K
#define PADBM    256                    // expert segment padding (= BM of GEMM tiles)
#define PADP     (NPAIR + NE * PADBM)   // 18432 worst-case padded rows
#define RT_MAX   (PADP / PADBM)         // 72 max row tiles

// 256x256x64 8-phase GEMM geometry
#define BM2 256
#define BN2 256
#define BK2 64
#define NTHR 512
#define NKT_UP (H_DIM / BK2)            // 32
#define NKT_DN (I_DIM / BK2)            // 64
#define NTN_UP (I_DIM / BN2)            // 16
#define NTN_DN (H_DIM / BN2)            // 8
#define TILE_B 32768                    // bytes per 256x64 bf16 operand tile
#define TILE_S 16384                    // shorts per tile

// ---------------- workspace layout (bytes) ----------------
// Ab (tiled gathered x) 75.5MB  [reused as Yb 67MB after gemm_up]
// Wt (tiled weights)   134.2MB  [up -> down]
// Hb (tiled)           151.0MB
// tok 74KB | meta 128B            total ~361MB
#define WS_AB   0ull
#define WS_W    (WS_AB + (size_t)RT_MAX * NKT_UP * TILE_B)
#define WS_H    (WS_W + (size_t)NE * I_DIM * H_DIM * 2)
#define WS_TOK  (WS_H + (size_t)RT_MAX * NKT_DN * TILE_B)
#define WS_META (WS_TOK + (size_t)PADP * 4)

typedef __attribute__((ext_vector_type(8))) short bf16x8;   // 8 bf16 = 4 VGPRs
typedef __attribute__((ext_vector_type(4))) float f32x4;    // MFMA C/D

__device__ __forceinline__ unsigned short f2bf(float f) {
  union { float f; unsigned u; } a; a.f = f;
  unsigned r = a.u + 0x7fffu + ((a.u >> 16) & 1u);   // RNE
  return (unsigned short)(r >> 16);
}

__device__ __forceinline__ float b2f(unsigned short b) {
  union { unsigned u; float f; } a; a.u = ((unsigned)b) << 16;
  return a.f;
}

__device__ __forceinline__ bf16x8 pack8(float4 a, float4 b) {
  bf16x8 o;
  o[0] = (short)f2bf(a.x); o[1] = (short)f2bf(a.y);
  o[2] = (short)f2bf(a.z); o[3] = (short)f2bf(a.w);
  o[4] = (short)f2bf(b.x); o[5] = (short)f2bf(b.y);
  o[6] = (short)f2bf(b.z); o[7] = (short)f2bf(b.w);
  return o;
}

__device__ __forceinline__ void gload16(const void* g, void* l) {
  __builtin_amdgcn_global_load_lds(
      (const __attribute__((address_space(1))) unsigned int*)g,
      (__attribute__((address_space(3))) unsigned int*)l,
      16, 0, 0);
}

// ---------------- routing ----------------
__global__ void route_count(const int* __restrict__ idx, int* __restrict__ meta) {
  int i = blockIdx.x * blockDim.x + threadIdx.x;
  if (i < NPAIR) atomicAdd(&meta[idx[i]], 1);
}

__global__ void route_scan(int* __restrict__ meta) {
  if (threadIdx.x == 0 && blockIdx.x == 0) {
    int off = 0;
    for (int e = 0; e < NE; ++e) {
      meta[16 + e] = off;
      int c = meta[e];
      off += ((c + PADBM - 1) / PADBM) * PADBM;
    }
    meta[16 + NE] = off;
  }
}

__global__ void route_scatter(const int* __restrict__ idx,
                              int* __restrict__ meta, int* __restrict__ tok) {
  int i = blockIdx.x * blockDim.x + threadIdx.x;
  if (i < NPAIR) {
    int e = idx[i];
    int pos = meta[16 + e] + atomicAdd(&meta[8 + e], 1);
    tok[pos] = i;                       // pair index; token = i>>1 (TOP_K=2)
  }
}

// ---------------- weight fp32 -> tiled bf16 ----------------
// out layout: [panel = e*NB+nb][kt][c=0..7][r=0..255][8 shorts], tile = 32KB.
__global__ __launch_bounds__(512) void cvt_tile_w(
    const float* __restrict__ W, unsigned short* __restrict__ out,
    int NKT, int K) {
  int tile = blockIdx.x;
  int kt = tile % NKT, panel = tile / NKT;
  const float* src = W + (size_t)panel * 256 * K + (size_t)kt * 64;
  unsigned short* dst = out + (size_t)tile * TILE_S;
  #pragma unroll
  for (int it = 0; it < 4; ++it) {
    int g = it * 512 + threadIdx.x;
    int c = g >> 8, r = g & 255;
    const float* s_ = src + (size_t)r * K + c * 8;
    float4 v0 = ((const float4*)s_)[0];
    float4 v1 = ((const float4*)s_)[1];
    *(bf16x8*)(dst + g * 8) = pack8(v0, v1);
  }
}

// ---------------- gathered x fp32 -> tiled bf16 A (fused gather+cvt) ----------------
__global__ __launch_bounds__(512) void gather_tile_x(
    const float* __restrict__ x, const int* __restrict__ tok,
    unsigned short* __restrict__ out) {
  int bid = blockIdx.x;                 // rt*NKT_UP + kt
  int rt = bid / NKT_UP, kt = bid % NKT_UP;
  unsigned short* dst = out + (size_t)bid * TILE_S;
  #pragma unroll
  for (int it = 0; it < 4; ++it) {
    int g = it * 512 + threadIdx.x;
    int c = g >> 8, r = g & 255;
    int v = tok[rt * 256 + r];
    bf16x8 o;
    if (v < 0) {
      o = (bf16x8)0;
    } else {
      const float* s_ = x + (size_t)(v >> 1) * H_DIM + kt * 64 + c * 8;
      o = pack8(((const float4*)s_)[0], ((const float4*)s_)[1]);
    }
    *(bf16x8*)(dst + g * 8) = o;
  }
}

// ---------------- 8-phase 256^2 grouped-GEMM core (linear tiled staging) ----------------
// LDS: A dbuf [2][32KB] at 0; B dbuf at 65536. Stage = linear 32KB copy per operand.
// Per-thread issue order A0,B0,A1,B1,A2,B2,A3,B3: first 4 done <=> ks=0 chunks of
// both operands staged. vmcnt(8)@c1 (tile t fully done; 8 newest = t+1's),
// vmcnt(4)@c3 (ks=0 of t+1 done). Never drains to 0 in main loop.

#define STAGE_FULL(KT, BS) do {                                                \
    const char* aT_ = aTile + (size_t)(KT) * TILE_B;                           \
    const char* bT_ = bTile + (size_t)(KT) * TILE_B;                           \
    _Pragma("unroll")                                                          \
    for (int l_ = 0; l_ < 4; ++l_) {                                           \
      int off_ = (l_ * 8 + wv) * 1024 + lane16;                                \
      gload16(aT_ + off_, smem + (BS) * 32768 + off_);                         \
      gload16(bT_ + off_, smem + 65536 + (BS) * 32768 + off_);                 \
    }                                                                          \
  } while (0)

#define PHASE(KS, FH, DO_STAGE, DO_VM) do {                                    \
    bf16x8 af[4];                                                              \
    const char* aB_ = smem + bufc * 32768 + ((KS) * 4 + hi) * 4096;            \
    _Pragma("unroll")                                                          \
    for (int f = 0; f < 4; ++f)                                                \
      af[f] = *(const bf16x8*)(aB_ + arow_b + ((FH) * 4 + f) * 256);           \
    if ((FH) == 0) {                                                           \
      const char* bB_ = smem + 65536 + bufc * 32768 + ((KS) * 4 + hi) * 4096;  \
      _Pragma("unroll")                                                        \
      for (int f = 0; f < 4; ++f)                                              \
        bfr[f] = *(const bf16x8*)(bB_ + brow_b + f * 256);                     \
    }                                                                          \
    DO_STAGE;                                                                  \
    DO_VM;                                                                     \
    __builtin_amdgcn_s_barrier();                                              \
    asm volatile("s_waitcnt lgkmcnt(0)" ::: "memory");                         \
    __builtin_amdgcn_s_setprio(1);                                             \
    _Pragma("unroll")                                                          \
    for (int fm = 0; fm < 4; ++fm)                                             \
      _Pragma("unroll")                                                        \
      for (int fn = 0; fn < 4; ++fn)                                           \
        acc[(FH) * 4 + fm][fn] = __builtin_amdgcn_mfma_f32_16x16x32_bf16(      \
            af[fm], bfr[fn], acc[(FH) * 4 + fm][fn], 0, 0, 0);                 \
    __builtin_amdgcn_s_setprio(0);                                             \
    __builtin_amdgcn_s_barrier();                                              \
  } while (0)

#define GEMM_PROLOGUE()                                                        \
  STAGE_FULL(0, 0);                                                            \
  asm volatile("s_waitcnt vmcnt(4)" ::: "memory");                             \
  __builtin_amdgcn_s_barrier();

#define GEMM_MAIN(NKT)                                                         \
  int bufc = 0;                                                                \
  for (int kt = 0; kt < (NKT); ++kt) {                                         \
    int ktn = (kt + 1 < (NKT)) ? kt + 1 : (NKT) - 1;  /* clamp: uniform counts */\
    int bn_ = bufc ^ 1;                                                        \
    PHASE(0, 0, STAGE_FULL(ktn, bn_), (void)0);                                \
    PHASE(0, 1, (void)0,                                                       \
          asm volatile("s_waitcnt vmcnt(8)" ::: "memory"));                    \
    PHASE(1, 0, (void)0, (void)0);                                             \
    PHASE(1, 1, (void)0,                                                       \
          asm volatile("s_waitcnt vmcnt(4)" ::: "memory"));                    \
    bufc ^= 1;                                                                 \
  }

// ---------------- GEMM1: h = relu2(A_tiled @ up_tiled^T), Hb written TILED ----------------
__global__ __launch_bounds__(NTHR, 2) void gemm_up8(
    const unsigned short* __restrict__ Ab, const unsigned short* __restrict__ Wt,
    unsigned short* __restrict__ Hb, const int* __restrict__ meta) {
  extern __shared__ char smem[];
  const int* pstart = meta + 16;
  int rt = blockIdx.x / NTN_UP, nt = blockIdx.x % NTN_UP;
  int row0 = rt * BM2;
  if (row0 >= pstart[NE]) return;
  int e = 0;
  #pragma unroll
  for (int q = 1; q < NE; ++q) if (row0 >= pstart[q]) e = q;

  int tid = threadIdx.x;
  int wv = tid >> 6, lane = tid & 63;
  int lane16 = lane * 16;

  const char* aTile = (const char*)Ab + (size_t)rt * NKT_UP * TILE_B;
  const char* bTile = (const char*)Wt + (size_t)(e * NTN_UP + nt) * NKT_UP * TILE_B;

  int wm = wv >> 2, wn = wv & 3;
  int hi = lane >> 4;
  int arow_b = (wm * 128 + (lane & 15)) * 16;   // byte offset of frag row base
  int brow_b = (wn * 64 + (lane & 15)) * 16;

  f32x4 acc[8][4] = {};
  bf16x8 bfr[4];

  GEMM_PROLOGUE();
  GEMM_MAIN(NKT_UP);                    // 32 K-tiles

  // epilogue: relu2 -> bf16 -> Hb tiled [rt][kt_dn][c][r][8]
  // kt_dn = nt*4 + wn (const), c = fn*2 + ((lane&15)>>3), s = lane&7,
  // r = wm*128 + hi*4 + fm*16 + j
  unsigned short* baseT = Hb + ((size_t)rt * NKT_DN + nt * 4 + wn) * TILE_S
                             + ((lane & 15) >> 3) * 2048 + (lane & 7);
  #pragma unroll
  for (int fm = 0; fm < 8; ++fm) {
    #pragma unroll
    for (int j = 0; j < 4; ++j) {
      int r = wm * 128 + hi * 4 + fm * 16 + j;
      unsigned short* rb = baseT + r * 8;
      #pragma unroll
      for (int fn = 0; fn < 4; ++fn) {
        float v = acc[fm][fn][j];
        v = v > 0.f ? v * v : 0.f;
        rb[fn * 4096] = f2bf(v);        // fn*2 chunks * 2048 shorts
      }
    }
  }
}

// ---------------- GEMM2: ybuf[pair] = h @ down_tiled^T ----------------
__global__ __launch_bounds__(NTHR, 2) void gemm_down8(
    const unsigned short* __restrict__ Hb, const unsigned short* __restrict__ Wt,
    unsigned short* __restrict__ Yb, const int* __restrict__ meta,
    const int* __restrict__ tok) {
  extern __shared__ char smem[];
  const int* pstart = meta + 16;
  int rt = blockIdx.x / NTN_DN, nt = blockIdx.x % NTN_DN;
  int row0 = rt * BM2;
  if (row0 >= pstart[NE]) return;
  int e = 0;
  #pragma unroll
  for (int q = 1; q < NE; ++q) if (row0 >= pstart[q]) e = q;

  int tid = threadIdx.x;
  int wv = tid >> 6, lane = tid & 63;
  int lane16 = lane * 16;

  const char* aTile = (const char*)Hb + (size_t)rt * NKT_DN * TILE_B;
  const char* bTile = (const char*)Wt + (size_t)(e * NTN_DN + nt) * NKT_DN * TILE_B;

  int wm = wv >> 2, wn = wv & 3;
  int hi = lane >> 4;
  int arow_b = (wm * 128 + (lane & 15)) * 16;
  int brow_b = (wn * 64 + (lane & 15)) * 16;

  f32x4 acc[8][4] = {};
  bf16x8 bfr[4];

  GEMM_PROLOGUE();
  GEMM_MAIN(NKT_DN);                    // 64 K-tiles

  int crow0 = row0 + wm * 128 + hi * 4;
  int ccol0 = nt * BN2 + wn * 64 + (lane & 15);
  #pragma unroll
  for (int fm = 0; fm < 8; ++fm) {
    #pragma unroll
    for (int j = 0; j < 4; ++j) {
      int p = crow0 + fm * 16 + j;
      int i = tok[p];
      if (i < 0) continue;              // padding row
      unsigned short* dst = Yb + (size_t)i * H_DIM + ccol0;
      #pragma unroll
      for (int fn = 0; fn < 4; ++fn)
        dst[fn * 16] = f2bf(acc[fm][fn][j]);
    }
  }
}

// ---------------- combine: out[t] = w0*y[2t] + w1*y[2t+1] ----------------
__global__ __launch_bounds__(256) void combine(
    const unsigned short* __restrict__ Yb, const float* __restrict__ tkw,
    float* __restrict__ out) {
  int t = blockIdx.x;
  int h0 = threadIdx.x * 8;
  float w0 = tkw[2 * t], w1 = tkw[2 * t + 1];
  bf16x8 ya = *(const bf16x8*)(Yb + (size_t)(2 * t) * H_DIM + h0);
  bf16x8 yb = *(const bf16x8*)(Yb + (size_t)(2 * t + 1) * H_DIM + h0);
  float* dst = out + (size_t)t * H_DIM + h0;
  float4 o0, o1;
  o0.x = w0 * b2f((unsigned short)ya[0]) + w1 * b2f((unsigned short)yb[0]);
  o0.y = w0 * b2f((unsigned short)ya[1]) + w1 * b2f((unsigned short)yb[1]);
  o0.z = w0 * b2f((unsigned short)ya[2]) + w1 * b2f((unsigned short)yb[2]);
  o0.w = w0 * b2f((unsigned short)ya[3]) + w1 * b2f((unsigned short)yb[3]);
  o1.x = w0 * b2f((unsigned short)ya[4]) + w1 * b2f((unsigned short)yb[4]);
  o1.y = w0 * b2f((unsigned short)ya[5]) + w1 * b2f((unsigned short)yb[5]);
  o1.z = w0 * b2f((unsigned short)ya[6]) + w1 * b2f((unsigned short)yb[6]);
  o1.w = w0 * b2f((unsigned short)ya[7]) + w1 * b2f((unsigned short)yb[7]);
  ((float4*)dst)[0] = o0;
  ((float4*)dst)[1] = o1;
}

// ---------------- launch ----------------
extern "C" void kernel_launch(void* const* d_in, const int* in_sizes, int n_in,
                              void* d_out, int out_size, void* d_ws, size_t ws_size,
                              hipStream_t stream) {
  const float* x   = (const float*)d_in[0];
  const int*   tki = (const int*)d_in[1];
  const float* tkw = (const float*)d_in[2];
  const float* up  = (const float*)d_in[3];
  const float* dn  = (const float*)d_in[4];
  float* out = (float*)d_out;
  char* ws = (char*)d_ws;

  unsigned short* ab  = (unsigned short*)(ws + WS_AB);   // tiled A (up)
  unsigned short* wt  = (unsigned short*)(ws + WS_W);    // tiled weights (up->down)
  unsigned short* hb  = (unsigned short*)(ws + WS_H);    // tiled H
  int*            tok = (int*)(ws + WS_TOK);
  unsigned short* yb  = (unsigned short*)(ws + WS_AB);   // Yb overlaps dead Ab
  int*            meta= (int*)(ws + WS_META);

  hipFuncSetAttribute((const void*)gemm_up8,
                      hipFuncAttributeMaxDynamicSharedMemorySize, 131072);
  hipFuncSetAttribute((const void*)gemm_down8,
                      hipFuncAttributeMaxDynamicSharedMemorySize, 131072);

  hipMemsetAsync(meta, 0, 128, stream);
  hipMemsetAsync(tok, 0xFF, (size_t)PADP * 4, stream);    // -1 = padding

  route_count  <<<NPAIR / 256, 256, 0, stream>>>(tki, meta);
  route_scan   <<<1, 64, 0, stream>>>(meta);
  route_scatter<<<NPAIR / 256, 256, 0, stream>>>(tki, meta, tok);

  gather_tile_x<<<RT_MAX * NKT_UP, 512, 0, stream>>>(x, tok, ab);
  cvt_tile_w   <<<NE * NTN_UP * NKT_UP, 512, 0, stream>>>(up, wt, NKT_UP, H_DIM);

  gemm_up8<<<RT_MAX * NTN_UP, NTHR, 131072, stream>>>(ab, wt, hb, meta);

  cvt_tile_w   <<<NE * NTN_DN * NKT_DN, 512, 0, stream>>>(dn, wt, NKT_DN, I_DIM);

  gemm_down8<<<RT_MAX * NTN_DN, NTHR, 131072, stream>>>(hb, wt, yb, meta, tok);

  combine<<<T_TOKENS, 256, 0, stream>>>(yb, tkw, out);
}